// Round 1
// baseline (523.218 us; speedup 1.0000x reference)
//
#include <hip/hip_runtime.h>
#include <stdint.h>

#define B_SZ   4096
#define OBS    512
#define T_TASKS 10
#define E_EXP  8
#define W_DIM  1024
#define H_OUT  12
#define XROW   522      // OBS + T
#define NTOT   8192     // E*W

using f32x4  = __attribute__((ext_vector_type(4))) float;
using bf16x8 = __attribute__((ext_vector_type(8))) short;

__device__ __forceinline__ unsigned short f2bf(float f) {
  union { float f; unsigned u; } x; x.f = f;
  unsigned r = x.u + 0x7FFF + ((x.u >> 16) & 1);   // RNE
  return (unsigned short)(r >> 16);
}
__device__ __forceinline__ float bf2f(unsigned short h) {
  union { unsigned u; float f; } x; x.u = ((unsigned)h) << 16;
  return x.f;
}

__device__ __forceinline__ void gload_lds16(const void* g, void* l) {
  __builtin_amdgcn_global_load_lds(
      (const __attribute__((address_space(1))) void*)g,
      (__attribute__((address_space(3))) void*)l,
      16, 0, 0);
}

// ---------------- prep kernels ----------------

__global__ void k_obs_bf16(const float* __restrict__ x, unsigned short* __restrict__ obsB) {
  int i = blockIdx.x * 256 + threadIdx.x;          // over B*OBS, exact grid
  int b = i >> 9, c = i & 511;
  obsB[i] = f2bf(x[(size_t)b * XROW + c]);
}

// W [e][K][1024] f32  ->  Wt [e][1024][K] bf16
__global__ void k_wt(const float* __restrict__ Wsrc, unsigned short* __restrict__ Wt, int K) {
  __shared__ float tile[32][33];
  int e  = blockIdx.z;
  int n0 = blockIdx.x * 32, k0 = blockIdx.y * 32;
  const float* Ws = Wsrc + (size_t)e * K * W_DIM;
  unsigned short* Wd = Wt + (size_t)e * W_DIM * K;
  int tx = threadIdx.x & 31, ty = threadIdx.x >> 5;   // ty 0..7
#pragma unroll
  for (int r = 0; r < 4; ++r)
    tile[ty + r * 8][tx] = Ws[(size_t)(k0 + ty + r * 8) * W_DIM + n0 + tx];
  __syncthreads();
#pragma unroll
  for (int r = 0; r < 4; ++r)
    Wd[(size_t)(n0 + ty + r * 8) * K + k0 + tx] = f2bf(tile[tx][ty + r * 8]);
}

// ---------------- GEMM: C[b][e*1024+n] = act( A[b][:]_e @ Wt[e][n][:] + bias[e][n] ) ----------------

template <bool RELU, bool OUTBF16>
__global__ __launch_bounds__(256, 2) void k_gemm(
    const unsigned short* __restrict__ A, int lda, int aExpStride,
    const unsigned short* __restrict__ Bt, int K,
    const float* __restrict__ bias,
    void* __restrict__ C)
{
  __shared__ short lA[4096];   // [128 rows][32 k] swizzled chunks
  __shared__ short lB[4096];   // [128 n   ][32 k]

  int bx   = blockIdx.x;
  int mblk = bx >> 6, nblk = bx & 63;
  int m0 = mblk * 128, n0g = nblk * 128;
  int e = n0g >> 10, n0e = n0g & 1023;

  const unsigned short* Ab = A + (size_t)e * aExpStride;
  const unsigned short* Bb = Bt + ((size_t)e * 1024 + n0e) * (size_t)K;

  int tid  = threadIdx.x;
  int lane = tid & 63, wid = tid >> 6;
  int wroff = (wid >> 1) * 64, wcoff = (wid & 1) * 64;

  // staging coords: 512 chunks of 16B per tile, 2 per thread
  int cl0 = tid, cl1 = 256 + tid;
  int row0 = cl0 >> 2, kl0 = cl0 & 3;
  int row1 = cl1 >> 2, kl1 = cl1 & 3;
  int kof0 = kl0 ^ ((row0 >> 1) & 3);    // pre-swizzled global source (rule #21)
  int kof1 = kl1 ^ ((row1 >> 1) & 3);

  // read-side swizzle
  int rlo = lane & 15;
  int kg  = lane >> 4;
  int kread = kg ^ ((rlo >> 1) & 3);

  f32x4 acc[4][4];
#pragma unroll
  for (int i = 0; i < 4; ++i)
#pragma unroll
    for (int j = 0; j < 4; ++j) acc[i][j] = f32x4{0.f, 0.f, 0.f, 0.f};

  const size_t ldaz = (size_t)lda;
  for (int k0 = 0; k0 < K; k0 += 32) {
    gload_lds16(Ab + (size_t)(m0 + row0) * ldaz + k0 + kof0 * 8, &lA[cl0 * 8]);
    gload_lds16(Ab + (size_t)(m0 + row1) * ldaz + k0 + kof1 * 8, &lA[cl1 * 8]);
    gload_lds16(Bb + (size_t)row0 * K + k0 + kof0 * 8, &lB[cl0 * 8]);
    gload_lds16(Bb + (size_t)row1 * K + k0 + kof1 * 8, &lB[cl1 * 8]);
    __syncthreads();

    bf16x8 af[4], bfv[4];
#pragma unroll
    for (int mi = 0; mi < 4; ++mi) {
      int row = wroff + mi * 16 + rlo;
      af[mi] = *(const bf16x8*)&lA[row * 32 + kread * 8];
    }
#pragma unroll
    for (int ni = 0; ni < 4; ++ni) {
      int row = wcoff + ni * 16 + rlo;
      bfv[ni] = *(const bf16x8*)&lB[row * 32 + kread * 8];
    }
#pragma unroll
    for (int mi = 0; mi < 4; ++mi)
#pragma unroll
      for (int ni = 0; ni < 4; ++ni)
        acc[mi][ni] = __builtin_amdgcn_mfma_f32_16x16x32_bf16(af[mi], bfv[ni], acc[mi][ni], 0, 0, 0);
    __syncthreads();
  }

  int rbase = (lane >> 4) * 4;
#pragma unroll
  for (int ni = 0; ni < 4; ++ni) {
    int colg = n0g + wcoff + ni * 16 + rlo;
    float bv = bias[e * W_DIM + (n0e + wcoff + ni * 16 + rlo)];
#pragma unroll
    for (int mi = 0; mi < 4; ++mi) {
      int rowg = m0 + wroff + mi * 16 + rbase;
#pragma unroll
      for (int j = 0; j < 4; ++j) {
        float v = acc[mi][ni][j] + bv;
        if (RELU) v = fmaxf(v, 0.0f);
        if (OUTBF16)
          ((unsigned short*)C)[(size_t)(rowg + j) * NTOT + colg] = f2bf(v);
        else
          ((float*)C)[(size_t)(rowg + j) * NTOT + colg] = v;
      }
    }
  }
}

// ---------------- Gram-Schmidt + feat + head ----------------

__device__ __forceinline__ float block_reduce(float v, float* scratch) {
  int lane = threadIdx.x & 63, wid = threadIdx.x >> 6;
#pragma unroll
  for (int o = 32; o > 0; o >>= 1) v += __shfl_down(v, o, 64);
  __syncthreads();                 // protect scratch from previous use
  if (lane == 0) scratch[wid] = v;
  __syncthreads();
  return scratch[0] + scratch[1] + scratch[2] + scratch[3];
}

__global__ __launch_bounds__(256) void k_gs(
    const unsigned short* __restrict__ eo,   // [B][8192] bf16
    const float* __restrict__ x,
    const float* __restrict__ te_W,          // [10][8]
    const float* __restrict__ head_W,        // [10][1024][12]
    const float* __restrict__ head_b,        // [10][12]
    float* __restrict__ out)                 // [B][12]
{
  __shared__ float V[NTOT];        // 32 KB
  __shared__ float red[4];
  __shared__ float red12[4][12];

  int b = blockIdx.x;
  int tid = threadIdx.x;

  for (int c = tid; c < NTOT; c += 256) V[c] = bf2f(eo[(size_t)b * NTOT + c]);

  // task id = argmax of exact one-hot
  int idx = 0; float mv = x[(size_t)b * XROW + OBS];
  for (int t = 1; t < T_TASKS; ++t) {
    float v = x[(size_t)b * XROW + OBS + t];
    if (v > mv) { mv = v; idx = t; }
  }
  __syncthreads();

  float cf[8];
  for (int i = 0; i < E_EXP; ++i) {
    float* Vi = V + i * 1024;
    for (int j = 0; j < i; ++j) {                   // classical GS: coeffs vs ORIGINAL v
      const float* Vj = V + j * 1024;
      float p = 0.f;
      for (int c = tid; c < 1024; c += 256) p += Vi[c] * Vj[c];
      cf[j] = block_reduce(p, red);
    }
    for (int c = tid; c < 1024; c += 256) {
      float w = Vi[c];
      for (int j = 0; j < i; ++j) w -= cf[j] * V[j * 1024 + c];
      Vi[c] = w;
    }
    float p = 0.f;
    for (int c = tid; c < 1024; c += 256) { float w = Vi[c]; p += w * w; }
    float nrm = sqrtf(block_reduce(p, red));
    float s = 1.0f / (nrm + 1e-8f);
    for (int c = tid; c < 1024; c += 256) Vi[c] *= s;
    __syncthreads();
  }

  float te[8];
#pragma unroll
  for (int e2 = 0; e2 < 8; ++e2) te[e2] = te_W[idx * E_EXP + e2];

  float ph[12];
#pragma unroll
  for (int h = 0; h < 12; ++h) ph[h] = 0.f;
  const float* hw = head_W + (size_t)idx * W_DIM * H_OUT;

  for (int c = tid; c < 1024; c += 256) {
    float f = 0.f;
#pragma unroll
    for (int e2 = 0; e2 < 8; ++e2) f += te[e2] * V[e2 * 1024 + c];
    f = tanhf(f);
#pragma unroll
    for (int h = 0; h < 12; ++h) ph[h] += f * hw[c * H_OUT + h];
  }

  int lane = tid & 63, wid = tid >> 6;
#pragma unroll
  for (int h = 0; h < 12; ++h) {
    float v = ph[h];
#pragma unroll
    for (int o = 32; o > 0; o >>= 1) v += __shfl_down(v, o, 64);
    if (lane == 0) red12[wid][h] = v;
  }
  __syncthreads();
  if (tid < 12) {
    float v = red12[0][tid] + red12[1][tid] + red12[2][tid] + red12[3][tid]
            + head_b[idx * H_OUT + tid];
    out[(size_t)b * H_OUT + tid] = v;
  }
}

// ---------------- launch ----------------

extern "C" void kernel_launch(void* const* d_in, const int* in_sizes, int n_in,
                              void* d_out, int out_size, void* d_ws, size_t ws_size,
                              hipStream_t stream) {
  const float* x     = (const float*)d_in[0];
  const float* te_W  = (const float*)d_in[1];
  const float* W0    = (const float*)d_in[2];
  const float* b0    = (const float*)d_in[3];
  const float* W1    = (const float*)d_in[4];
  const float* b1    = (const float*)d_in[5];
  const float* W2    = (const float*)d_in[6];
  const float* b2    = (const float*)d_in[7];
  const float* headW = (const float*)d_in[8];
  const float* headb = (const float*)d_in[9];
  float* out = (float*)d_out;

  char* ws = (char*)d_ws;
  size_t off = 0;
  auto alloc = [&](size_t bytes) {
    void* p = ws + off;
    off += (bytes + 255) & ~(size_t)255;
    return p;
  };
  unsigned short* obsB = (unsigned short*)alloc((size_t)B_SZ * OBS * 2);
  unsigned short* W0t  = (unsigned short*)alloc((size_t)8 * 1024 * 512 * 2);
  unsigned short* W1t  = (unsigned short*)alloc((size_t)8 * 1024 * 1024 * 2);
  unsigned short* W2t  = (unsigned short*)alloc((size_t)8 * 1024 * 1024 * 2);
  unsigned short* h0   = (unsigned short*)alloc((size_t)B_SZ * NTOT * 2);
  unsigned short* h1   = (unsigned short*)alloc((size_t)B_SZ * NTOT * 2);
  unsigned short* eo   = (unsigned short*)alloc((size_t)B_SZ * NTOT * 2);
  (void)ws_size; (void)in_sizes; (void)n_in; (void)out_size;

  k_obs_bf16<<<(B_SZ * OBS) / 256, 256, 0, stream>>>(x, obsB);
  k_wt<<<dim3(32, 16, 8), 256, 0, stream>>>(W0, W0t, 512);
  k_wt<<<dim3(32, 32, 8), 256, 0, stream>>>(W1, W1t, 1024);
  k_wt<<<dim3(32, 32, 8), 256, 0, stream>>>(W2, W2t, 1024);

  k_gemm<true,  true><<<2048, 256, 0, stream>>>(obsB, 512,  0,    W0t, 512,  b0, h0);
  k_gemm<true,  true><<<2048, 256, 0, stream>>>(h0,   NTOT, 1024, W1t, 1024, b1, h1);
  k_gemm<false, true><<<2048, 256, 0, stream>>>(h1,   NTOT, 1024, W2t, 1024, b2, eo);

  k_gs<<<B_SZ, 256, 0, stream>>>(eo, x, te_W, headW, headb, out);
}

// Round 2
// 381.129 us; speedup vs baseline: 1.3728x; 1.3728x over previous
//
#include <hip/hip_runtime.h>
#include <stdint.h>

#define B_SZ   4096
#define OBS    512
#define T_TASKS 10
#define E_EXP  8
#define W_DIM  1024
#define H_OUT  12
#define XROW   522      // OBS + T
#define NTOT   8192     // E*W

using f32x4  = __attribute__((ext_vector_type(4))) float;
using bf16x8 = __attribute__((ext_vector_type(8))) short;

__device__ __forceinline__ unsigned short f2bf(float f) {
  union { float f; unsigned u; } x; x.f = f;
  unsigned r = x.u + 0x7FFF + ((x.u >> 16) & 1);   // RNE
  return (unsigned short)(r >> 16);
}
__device__ __forceinline__ float bf2f(unsigned short h) {
  union { unsigned u; float f; } x; x.u = ((unsigned)h) << 16;
  return x.f;
}

__device__ __forceinline__ void gload_lds16(const void* g, void* l) {
  __builtin_amdgcn_global_load_lds(
      (const __attribute__((address_space(1))) void*)g,
      (__attribute__((address_space(3))) void*)l,
      16, 0, 0);
}

// ---------------- prep kernels ----------------

__global__ void k_obs_bf16(const float* __restrict__ x, unsigned short* __restrict__ obsB) {
  int i = blockIdx.x * 256 + threadIdx.x;          // over B*OBS, exact grid
  int b = i >> 9, c = i & 511;
  obsB[i] = f2bf(x[(size_t)b * XROW + c]);
}

// W [e][K][1024] f32  ->  Wt [e][1024][K] bf16
__global__ void k_wt(const float* __restrict__ Wsrc, unsigned short* __restrict__ Wt, int K) {
  __shared__ float tile[32][33];
  int e  = blockIdx.z;
  int n0 = blockIdx.x * 32, k0 = blockIdx.y * 32;
  const float* Ws = Wsrc + (size_t)e * K * W_DIM;
  unsigned short* Wd = Wt + (size_t)e * W_DIM * K;
  int tx = threadIdx.x & 31, ty = threadIdx.x >> 5;   // ty 0..7
#pragma unroll
  for (int r = 0; r < 4; ++r)
    tile[ty + r * 8][tx] = Ws[(size_t)(k0 + ty + r * 8) * W_DIM + n0 + tx];
  __syncthreads();
#pragma unroll
  for (int r = 0; r < 4; ++r)
    Wd[(size_t)(n0 + ty + r * 8) * K + k0 + tx] = f2bf(tile[tx][ty + r * 8]);
}

// ---------------- GEMM: C[b][e*1024+n] = act( A[b][:]_e @ Wt[e][n][:] + bias[e][n] ) ----------------

template <bool RELU, bool OUTBF16>
__global__ __launch_bounds__(256, 2) void k_gemm(
    const unsigned short* __restrict__ A, int lda, int aExpStride,
    const unsigned short* __restrict__ Bt, int K,
    const float* __restrict__ bias,
    void* __restrict__ C)
{
  __shared__ short lA[4096];   // [128 rows][32 k] swizzled chunks
  __shared__ short lB[4096];   // [128 n   ][32 k]

  int bx   = blockIdx.x;
  int mblk = bx >> 6, nblk = bx & 63;
  int m0 = mblk * 128, n0g = nblk * 128;
  int e = n0g >> 10, n0e = n0g & 1023;

  const unsigned short* Ab = A + (size_t)e * aExpStride;
  const unsigned short* Bb = Bt + ((size_t)e * 1024 + n0e) * (size_t)K;

  int tid  = threadIdx.x;
  int lane = tid & 63, wid = tid >> 6;
  int wroff = (wid >> 1) * 64, wcoff = (wid & 1) * 64;

  // staging coords: 512 chunks of 16B per tile, 2 per thread
  int cl0 = tid, cl1 = 256 + tid;
  int row0 = cl0 >> 2, kl0 = cl0 & 3;
  int row1 = cl1 >> 2, kl1 = cl1 & 3;
  int kof0 = kl0 ^ ((row0 >> 1) & 3);    // pre-swizzled global source (rule #21)
  int kof1 = kl1 ^ ((row1 >> 1) & 3);

  // read-side swizzle
  int rlo = lane & 15;
  int kg  = lane >> 4;
  int kread = kg ^ ((rlo >> 1) & 3);

  f32x4 acc[4][4];
#pragma unroll
  for (int i = 0; i < 4; ++i)
#pragma unroll
    for (int j = 0; j < 4; ++j) acc[i][j] = f32x4{0.f, 0.f, 0.f, 0.f};

  const size_t ldaz = (size_t)lda;
  for (int k0 = 0; k0 < K; k0 += 32) {
    gload_lds16(Ab + (size_t)(m0 + row0) * ldaz + k0 + kof0 * 8, &lA[cl0 * 8]);
    gload_lds16(Ab + (size_t)(m0 + row1) * ldaz + k0 + kof1 * 8, &lA[cl1 * 8]);
    gload_lds16(Bb + (size_t)row0 * K + k0 + kof0 * 8, &lB[cl0 * 8]);
    gload_lds16(Bb + (size_t)row1 * K + k0 + kof1 * 8, &lB[cl1 * 8]);
    __syncthreads();

    bf16x8 af[4], bfv[4];
#pragma unroll
    for (int mi = 0; mi < 4; ++mi) {
      int row = wroff + mi * 16 + rlo;
      af[mi] = *(const bf16x8*)&lA[row * 32 + kread * 8];
    }
#pragma unroll
    for (int ni = 0; ni < 4; ++ni) {
      int row = wcoff + ni * 16 + rlo;
      bfv[ni] = *(const bf16x8*)&lB[row * 32 + kread * 8];
    }
#pragma unroll
    for (int mi = 0; mi < 4; ++mi)
#pragma unroll
      for (int ni = 0; ni < 4; ++ni)
        acc[mi][ni] = __builtin_amdgcn_mfma_f32_16x16x32_bf16(af[mi], bfv[ni], acc[mi][ni], 0, 0, 0);
    __syncthreads();
  }

  int rbase = (lane >> 4) * 4;
#pragma unroll
  for (int ni = 0; ni < 4; ++ni) {
    int colg = n0g + wcoff + ni * 16 + rlo;
    float bv = bias[e * W_DIM + (n0e + wcoff + ni * 16 + rlo)];
#pragma unroll
    for (int mi = 0; mi < 4; ++mi) {
      int rowg = m0 + wroff + mi * 16 + rbase;
#pragma unroll
      for (int j = 0; j < 4; ++j) {
        float v = acc[mi][ni][j] + bv;
        if (RELU) v = fmaxf(v, 0.0f);
        if (OUTBF16)
          ((unsigned short*)C)[(size_t)(rowg + j) * NTOT + colg] = f2bf(v);
        else
          ((float*)C)[(size_t)(rowg + j) * NTOT + colg] = v;
      }
    }
  }
}

// ---------------- Gram-Schmidt + feat + head: one WAVE per batch row ----------------
// 8x1024 row lives entirely in registers (float v[8][16] per lane).
// All reductions are 6-step __shfl_xor butterflies: no LDS, no barriers.

__device__ __forceinline__ float wred(float s) {
#pragma unroll
  for (int m = 32; m; m >>= 1) s += __shfl_xor(s, m, 64);
  return s;
}

__global__ __launch_bounds__(256, 1) void k_gs_wave(
    const unsigned short* __restrict__ eo,   // [B][8192] bf16
    const float* __restrict__ x,
    const float* __restrict__ te_W,          // [10][8]
    const float* __restrict__ head_W,        // [10][1024][12]
    const float* __restrict__ head_b,        // [10][12]
    float* __restrict__ out)                 // [B][12]
{
  int wid = threadIdx.x >> 6, lane = threadIdx.x & 63;
  int b = blockIdx.x * 4 + wid;

  // load entire row: v[i][half*8+k] = eo[b][i*1024 + half*512 + lane*8 + k]
  float v[8][16];
  const unsigned short* row = eo + (size_t)b * NTOT;
#pragma unroll
  for (int i = 0; i < E_EXP; ++i) {
#pragma unroll
    for (int half = 0; half < 2; ++half) {
      bf16x8 t = *(const bf16x8*)&row[i * 1024 + half * 512 + lane * 8];
#pragma unroll
      for (int k = 0; k < 8; ++k) v[i][half * 8 + k] = bf2f((unsigned short)t[k]);
    }
  }

  // task id = argmax of exact one-hot (broadcast loads, all lanes same addr)
  int idx = 0; float mv = x[(size_t)b * XROW + OBS];
#pragma unroll
  for (int t = 1; t < T_TASKS; ++t) {
    float val = x[(size_t)b * XROW + OBS + t];
    if (val > mv) { mv = val; idx = t; }
  }

  // classical Gram-Schmidt, fully unrolled (static register indexing)
  float cf[7];
#pragma unroll
  for (int i = 0; i < E_EXP; ++i) {
#pragma unroll
    for (int j = 0; j < 7; ++j) {
      if (j < i) {
        float p = 0.f;
#pragma unroll
        for (int c = 0; c < 16; ++c) p += v[i][c] * v[j][c];
        cf[j] = wred(p);
      }
    }
#pragma unroll
    for (int c = 0; c < 16; ++c) {
      float w = v[i][c];
#pragma unroll
      for (int j = 0; j < 7; ++j)
        if (j < i) w -= cf[j] * v[j][c];
      v[i][c] = w;
    }
    float p = 0.f;
#pragma unroll
    for (int c = 0; c < 16; ++c) p += v[i][c] * v[i][c];
    float nrm = sqrtf(wred(p));
    float s = 1.0f / (nrm + 1e-8f);
#pragma unroll
    for (int c = 0; c < 16; ++c) v[i][c] *= s;
  }

  float te[E_EXP];
#pragma unroll
  for (int e2 = 0; e2 < E_EXP; ++e2) te[e2] = te_W[idx * E_EXP + e2];

  float ph[H_OUT];
#pragma unroll
  for (int h = 0; h < H_OUT; ++h) ph[h] = 0.f;
  const float* hw = head_W + (size_t)idx * W_DIM * H_OUT;

#pragma unroll
  for (int half = 0; half < 2; ++half) {
#pragma unroll
    for (int k = 0; k < 8; ++k) {
      int c = half * 512 + lane * 8 + k;
      float f = 0.f;
#pragma unroll
      for (int e2 = 0; e2 < E_EXP; ++e2) f += te[e2] * v[e2][half * 8 + k];
      f = tanhf(f);
      const float* hwc = hw + (size_t)c * H_OUT;
#pragma unroll
      for (int h = 0; h < H_OUT; ++h) ph[h] += f * hwc[h];
    }
  }

#pragma unroll
  for (int h = 0; h < H_OUT; ++h) ph[h] = wred(ph[h]);
  if (lane == 0) {
#pragma unroll
    for (int h = 0; h < H_OUT; ++h)
      out[(size_t)b * H_OUT + h] = ph[h] + head_b[idx * H_OUT + h];
  }
}

// ---------------- launch ----------------

extern "C" void kernel_launch(void* const* d_in, const int* in_sizes, int n_in,
                              void* d_out, int out_size, void* d_ws, size_t ws_size,
                              hipStream_t stream) {
  const float* x     = (const float*)d_in[0];
  const float* te_W  = (const float*)d_in[1];
  const float* W0    = (const float*)d_in[2];
  const float* b0    = (const float*)d_in[3];
  const float* W1    = (const float*)d_in[4];
  const float* b1    = (const float*)d_in[5];
  const float* W2    = (const float*)d_in[6];
  const float* b2    = (const float*)d_in[7];
  const float* headW = (const float*)d_in[8];
  const float* headb = (const float*)d_in[9];
  float* out = (float*)d_out;

  char* ws = (char*)d_ws;
  size_t off = 0;
  auto alloc = [&](size_t bytes) {
    void* p = ws + off;
    off += (bytes + 255) & ~(size_t)255;
    return p;
  };
  unsigned short* obsB = (unsigned short*)alloc((size_t)B_SZ * OBS * 2);
  unsigned short* W0t  = (unsigned short*)alloc((size_t)8 * 1024 * 512 * 2);
  unsigned short* W1t  = (unsigned short*)alloc((size_t)8 * 1024 * 1024 * 2);
  unsigned short* W2t  = (unsigned short*)alloc((size_t)8 * 1024 * 1024 * 2);
  unsigned short* h0   = (unsigned short*)alloc((size_t)B_SZ * NTOT * 2);
  unsigned short* h1   = (unsigned short*)alloc((size_t)B_SZ * NTOT * 2);
  unsigned short* eo   = (unsigned short*)alloc((size_t)B_SZ * NTOT * 2);
  (void)ws_size; (void)in_sizes; (void)n_in; (void)out_size;

  k_obs_bf16<<<(B_SZ * OBS) / 256, 256, 0, stream>>>(x, obsB);
  k_wt<<<dim3(32, 16, 8), 256, 0, stream>>>(W0, W0t, 512);
  k_wt<<<dim3(32, 32, 8), 256, 0, stream>>>(W1, W1t, 1024);
  k_wt<<<dim3(32, 32, 8), 256, 0, stream>>>(W2, W2t, 1024);

  k_gemm<true,  true><<<2048, 256, 0, stream>>>(obsB, 512,  0,    W0t, 512,  b0, h0);
  k_gemm<true,  true><<<2048, 256, 0, stream>>>(h0,   NTOT, 1024, W1t, 1024, b1, h1);
  k_gemm<false, true><<<2048, 256, 0, stream>>>(h1,   NTOT, 1024, W2t, 1024, b2, eo);

  k_gs_wave<<<B_SZ / 4, 256, 0, stream>>>(eo, x, te_W, headW, headb, out);
}

// Round 3
// 261.437 us; speedup vs baseline: 2.0013x; 1.4578x over previous
//
#include <hip/hip_runtime.h>
#include <stdint.h>

#define B_SZ   4096
#define OBS    512
#define T_TASKS 10
#define E_EXP  8
#define W_DIM  1024
#define H_OUT  12
#define XROW   522      // OBS + T
#define NTOT   8192     // E*W

using f32x4  = __attribute__((ext_vector_type(4))) float;
using bf16x8 = __attribute__((ext_vector_type(8))) short;

__device__ __forceinline__ unsigned short f2bf(float f) {
  union { float f; unsigned u; } x; x.f = f;
  unsigned r = x.u + 0x7FFF + ((x.u >> 16) & 1);   // RNE
  return (unsigned short)(r >> 16);
}
__device__ __forceinline__ float bf2f(unsigned short h) {
  union { unsigned u; float f; } x; x.u = ((unsigned)h) << 16;
  return x.f;
}

__device__ __forceinline__ void gload_lds16(const void* g, void* l) {
  __builtin_amdgcn_global_load_lds(
      (const __attribute__((address_space(1))) void*)g,
      (__attribute__((address_space(3))) void*)l,
      16, 0, 0);
}

// ---------------- prep kernels ----------------

__global__ void k_obs_bf16(const float* __restrict__ x, unsigned short* __restrict__ obsB) {
  int i = blockIdx.x * 256 + threadIdx.x;          // over B*OBS, exact grid
  int b = i >> 9, c = i & 511;
  obsB[i] = f2bf(x[(size_t)b * XROW + c]);
}

// W [e][K][1024] f32  ->  Wt [e][1024][K] bf16
__global__ void k_wt(const float* __restrict__ Wsrc, unsigned short* __restrict__ Wt, int K) {
  __shared__ float tile[32][33];
  int e  = blockIdx.z;
  int n0 = blockIdx.x * 32, k0 = blockIdx.y * 32;
  const float* Ws = Wsrc + (size_t)e * K * W_DIM;
  unsigned short* Wd = Wt + (size_t)e * W_DIM * K;
  int tx = threadIdx.x & 31, ty = threadIdx.x >> 5;   // ty 0..7
#pragma unroll
  for (int r = 0; r < 4; ++r)
    tile[ty + r * 8][tx] = Ws[(size_t)(k0 + ty + r * 8) * W_DIM + n0 + tx];
  __syncthreads();
#pragma unroll
  for (int r = 0; r < 4; ++r)
    Wd[(size_t)(n0 + ty + r * 8) * K + k0 + tx] = f2bf(tile[tx][ty + r * 8]);
}

// ---------------- 256x256 8-phase GEMM ----------------
// C[b][e*1024+n] = act( A[b][:]_e @ Bt[e][n][:] + bias[e][n] ), C bf16.
// 512 thr = 8 waves (2M x 4N). BK=64, dbuf LDS 128 KB.
// Interleaved wave mapping: frag row = mh*128 + mi*32 + wm*16, col = nh*128 + ni*64 + wn*16
// -> quadrant (mh,nh) touches exactly LDS halves (A-mh, B-nh): progressive consumption.
// Phases: P1(0,0) P2(0,1) P3(1,1) P4(1,0); stages (next tile): A0,B0,B1,A1; vmcnt(4) at P1,P2,P4.

template <bool RELU>
__global__ __launch_bounds__(512, 2) void k_gemm256(
    const unsigned short* __restrict__ A, int lda, int aExpStride,
    const unsigned short* __restrict__ Bt, int K,
    const float* __restrict__ bias,
    unsigned short* __restrict__ C)
{
  extern __shared__ char lds[];
  const int tid  = threadIdx.x;
  const int lane = tid & 63, wid = tid >> 6;
  const int wm = wid >> 2, wn = wid & 3;
  const int rlo = lane & 15, kg = lane >> 4;

  // bijective XCD swizzle: 512 blocks -> 8 XCDs x (8 mblk x 8 nblk)
  int bid = blockIdx.x;
  int xcd = bid & 7, loc = bid >> 3;
  int mblk = ((xcd & 1) << 3) | (loc & 7);
  int nblk = ((xcd >> 1) << 3) | (loc >> 3);
  int m0 = mblk * 256, n0g = nblk * 256;
  int e = n0g >> 10, n0e = n0g & 1023;

  const unsigned short* Ab = A + (size_t)e * aExpStride;
  const unsigned short* Bb = Bt + ((size_t)e * 1024 + n0e) * (size_t)K;

  // staging coords: half-tile = 128 rows x 8 chunks(16B) = 1024 chunks; 2/thread
  const int idx0 = tid, idx1 = 512 + tid;
  const int r0 = idx0 >> 3, p0 = idx0 & 7, c0 = p0 ^ (r0 & 7);  // inverse-swz source
  const int r1 = idx1 >> 3, p1 = idx1 & 7, c1 = p1 ^ (r1 & 7);

  const int NT = K >> 6;
  const size_t ldaz = (size_t)lda, ldkz = (size_t)K;

  auto stageA = [&](int buf, int h, int kt) {
    const unsigned short* g0 = Ab + (size_t)(m0 + h * 128 + r0) * ldaz + kt * 64 + c0 * 8;
    const unsigned short* g1 = Ab + (size_t)(m0 + h * 128 + r1) * ldaz + kt * 64 + c1 * 8;
    char* l = lds + buf * 65536 + h * 16384;
    gload_lds16(g0, l + idx0 * 16);
    gload_lds16(g1, l + idx1 * 16);
  };
  auto stageB = [&](int buf, int h, int kt) {
    const unsigned short* g0 = Bb + (size_t)(h * 128 + r0) * ldkz + kt * 64 + c0 * 8;
    const unsigned short* g1 = Bb + (size_t)(h * 128 + r1) * ldkz + kt * 64 + c1 * 8;
    char* l = lds + buf * 65536 + 32768 + h * 16384;
    gload_lds16(g0, l + idx0 * 16);
    gload_lds16(g1, l + idx1 * 16);
  };
  auto rdA = [&](int buf, int mh, int mi, int ks) -> bf16x8 {
    int r = mi * 32 + wm * 16 + rlo;
    int p = (ks * 4 + kg) ^ (r & 7);               // swizzled read
    return *(const bf16x8*)(lds + buf * 65536 + mh * 16384 + r * 128 + p * 16);
  };
  auto rdB = [&](int buf, int nh, int ni, int ks) -> bf16x8 {
    int r = ni * 64 + wn * 16 + rlo;
    int p = (ks * 4 + kg) ^ (r & 7);
    return *(const bf16x8*)(lds + buf * 65536 + 32768 + nh * 16384 + r * 128 + p * 16);
  };

  f32x4 acc[8][4];
#pragma unroll
  for (int i = 0; i < 8; ++i)
#pragma unroll
    for (int j = 0; j < 4; ++j) acc[i][j] = f32x4{0.f, 0.f, 0.f, 0.f};

  bf16x8 af[8], b0f[4], b1f[4];

  // prologue: tile 0 halves in order A0,B0,B1,A1 -> vmcnt(4) leaves B1,A1 in flight
  stageA(0, 0, 0); stageB(0, 0, 0); stageB(0, 1, 0); stageA(0, 1, 0);
  asm volatile("s_waitcnt vmcnt(4)" ::: "memory");
  __builtin_amdgcn_sched_barrier(0);
  asm volatile("s_barrier" ::: "memory");

  for (int t = 0; t < NT; ++t) {
    int buf = t & 1, nbuf = buf ^ 1, tn = t + 1;
    bool st = tn < NT;

    // ---- P1: (mh0, nh0) — reads A-h0 (8) + B-h0 (4) ----
#pragma unroll
    for (int mi = 0; mi < 4; ++mi)
#pragma unroll
      for (int ks = 0; ks < 2; ++ks) af[mi * 2 + ks] = rdA(buf, 0, mi, ks);
#pragma unroll
    for (int ni = 0; ni < 2; ++ni)
#pragma unroll
      for (int ks = 0; ks < 2; ++ks) b0f[ni * 2 + ks] = rdB(buf, 0, ni, ks);
    if (st) stageA(nbuf, 0, tn);
    asm volatile("s_waitcnt vmcnt(4)" ::: "memory");   // guards P2's B-h1
    __builtin_amdgcn_sched_barrier(0);
    asm volatile("s_barrier" ::: "memory");
    asm volatile("s_waitcnt lgkmcnt(0)" ::: "memory");
    __builtin_amdgcn_sched_barrier(0);
    __builtin_amdgcn_s_setprio(1);
#pragma unroll
    for (int ks = 0; ks < 2; ++ks)
#pragma unroll
      for (int mi = 0; mi < 4; ++mi)
#pragma unroll
        for (int ni = 0; ni < 2; ++ni)
          acc[mi][ni] = __builtin_amdgcn_mfma_f32_16x16x32_bf16(af[mi * 2 + ks], b0f[ni * 2 + ks], acc[mi][ni], 0, 0, 0);
    __builtin_amdgcn_s_setprio(0);
    __builtin_amdgcn_sched_barrier(0);
    asm volatile("s_barrier" ::: "memory");

    // ---- P2: (mh0, nh1) — reads B-h1 (4) ----
#pragma unroll
    for (int ni = 0; ni < 2; ++ni)
#pragma unroll
      for (int ks = 0; ks < 2; ++ks) b1f[ni * 2 + ks] = rdB(buf, 1, ni, ks);
    if (st) stageB(nbuf, 0, tn);
    asm volatile("s_waitcnt vmcnt(4)" ::: "memory");   // guards P3's A-h1
    __builtin_amdgcn_sched_barrier(0);
    asm volatile("s_barrier" ::: "memory");
    asm volatile("s_waitcnt lgkmcnt(0)" ::: "memory");
    __builtin_amdgcn_sched_barrier(0);
    __builtin_amdgcn_s_setprio(1);
#pragma unroll
    for (int ks = 0; ks < 2; ++ks)
#pragma unroll
      for (int mi = 0; mi < 4; ++mi)
#pragma unroll
        for (int ni = 0; ni < 2; ++ni)
          acc[mi][2 + ni] = __builtin_amdgcn_mfma_f32_16x16x32_bf16(af[mi * 2 + ks], b1f[ni * 2 + ks], acc[mi][2 + ni], 0, 0, 0);
    __builtin_amdgcn_s_setprio(0);
    __builtin_amdgcn_sched_barrier(0);
    asm volatile("s_barrier" ::: "memory");

    // ---- P3: (mh1, nh1) — reads A-h1 (8) ----
#pragma unroll
    for (int mi = 0; mi < 4; ++mi)
#pragma unroll
      for (int ks = 0; ks < 2; ++ks) af[mi * 2 + ks] = rdA(buf, 1, mi, ks);
    if (st) stageB(nbuf, 1, tn);
    __builtin_amdgcn_sched_barrier(0);                 // no vmcnt: P4 reads nothing new
    asm volatile("s_barrier" ::: "memory");
    asm volatile("s_waitcnt lgkmcnt(0)" ::: "memory");
    __builtin_amdgcn_sched_barrier(0);
    __builtin_amdgcn_s_setprio(1);
#pragma unroll
    for (int ks = 0; ks < 2; ++ks)
#pragma unroll
      for (int mi = 0; mi < 4; ++mi)
#pragma unroll
        for (int ni = 0; ni < 2; ++ni)
          acc[4 + mi][2 + ni] = __builtin_amdgcn_mfma_f32_16x16x32_bf16(af[mi * 2 + ks], b1f[ni * 2 + ks], acc[4 + mi][2 + ni], 0, 0, 0);
    __builtin_amdgcn_s_setprio(0);
    __builtin_amdgcn_sched_barrier(0);
    asm volatile("s_barrier" ::: "memory");

    // ---- P4: (mh1, nh0) — no new reads (af live, b0f live) ----
    if (st) stageA(nbuf, 1, tn);
    asm volatile("s_waitcnt vmcnt(4)" ::: "memory");   // guards next tile's P1 (A-h0,B-h0)
    __builtin_amdgcn_sched_barrier(0);
    asm volatile("s_barrier" ::: "memory");
    __builtin_amdgcn_s_setprio(1);
#pragma unroll
    for (int ks = 0; ks < 2; ++ks)
#pragma unroll
      for (int mi = 0; mi < 4; ++mi)
#pragma unroll
        for (int ni = 0; ni < 2; ++ni)
          acc[4 + mi][ni] = __builtin_amdgcn_mfma_f32_16x16x32_bf16(af[mi * 2 + ks], b0f[ni * 2 + ks], acc[4 + mi][ni], 0, 0, 0);
    __builtin_amdgcn_s_setprio(0);
    __builtin_amdgcn_sched_barrier(0);
    asm volatile("s_barrier" ::: "memory");
  }

  // epilogue: bias (+ReLU) + bf16 store
  int rbase = kg * 4;
#pragma unroll
  for (int fi = 0; fi < 8; ++fi) {
    int mh = fi >> 2, mi = fi & 3;
    int rowg = m0 + mh * 128 + mi * 32 + wm * 16 + rbase;
#pragma unroll
    for (int fj = 0; fj < 4; ++fj) {
      int nh = fj >> 1, ni = fj & 1;
      int colr = nh * 128 + ni * 64 + wn * 16 + rlo;
      int colg = n0g + colr;
      float bv = bias[e * W_DIM + n0e + colr];
#pragma unroll
      for (int j = 0; j < 4; ++j) {
        float v = acc[fi][fj][j] + bv;
        if (RELU) v = fmaxf(v, 0.0f);
        C[(size_t)(rowg + j) * NTOT + colg] = f2bf(v);
      }
    }
  }
}

// ---------------- Gram-Schmidt + feat + head: one WAVE per batch row ----------------

__device__ __forceinline__ float wred(float s) {
#pragma unroll
  for (int m = 32; m; m >>= 1) s += __shfl_xor(s, m, 64);
  return s;
}

__global__ __launch_bounds__(256, 1) void k_gs_wave(
    const unsigned short* __restrict__ eo,   // [B][8192] bf16
    const float* __restrict__ x,
    const float* __restrict__ te_W,          // [10][8]
    const float* __restrict__ head_W,        // [10][1024][12]
    const float* __restrict__ head_b,        // [10][12]
    float* __restrict__ out)                 // [B][12]
{
  int wid = threadIdx.x >> 6, lane = threadIdx.x & 63;
  int b = blockIdx.x * 4 + wid;

  float v[8][16];
  const unsigned short* row = eo + (size_t)b * NTOT;
#pragma unroll
  for (int i = 0; i < E_EXP; ++i) {
#pragma unroll
    for (int half = 0; half < 2; ++half) {
      bf16x8 t = *(const bf16x8*)&row[i * 1024 + half * 512 + lane * 8];
#pragma unroll
      for (int k = 0; k < 8; ++k) v[i][half * 8 + k] = bf2f((unsigned short)t[k]);
    }
  }

  int idx = 0; float mv = x[(size_t)b * XROW + OBS];
#pragma unroll
  for (int t = 1; t < T_TASKS; ++t) {
    float val = x[(size_t)b * XROW + OBS + t];
    if (val > mv) { mv = val; idx = t; }
  }

  float cf[7];
#pragma unroll
  for (int i = 0; i < E_EXP; ++i) {
#pragma unroll
    for (int j = 0; j < 7; ++j) {
      if (j < i) {
        float p = 0.f;
#pragma unroll
        for (int c = 0; c < 16; ++c) p += v[i][c] * v[j][c];
        cf[j] = wred(p);
      }
    }
#pragma unroll
    for (int c = 0; c < 16; ++c) {
      float w = v[i][c];
#pragma unroll
      for (int j = 0; j < 7; ++j)
        if (j < i) w -= cf[j] * v[j][c];
      v[i][c] = w;
    }
    float p = 0.f;
#pragma unroll
    for (int c = 0; c < 16; ++c) p += v[i][c] * v[i][c];
    float nrm = sqrtf(wred(p));
    float s = 1.0f / (nrm + 1e-8f);
#pragma unroll
    for (int c = 0; c < 16; ++c) v[i][c] *= s;
  }

  float te[E_EXP];
#pragma unroll
  for (int e2 = 0; e2 < E_EXP; ++e2) te[e2] = te_W[idx * E_EXP + e2];

  float ph[H_OUT];
#pragma unroll
  for (int h = 0; h < H_OUT; ++h) ph[h] = 0.f;
  const float* hw = head_W + (size_t)idx * W_DIM * H_OUT;

#pragma unroll
  for (int half = 0; half < 2; ++half) {
#pragma unroll
    for (int k = 0; k < 8; ++k) {
      int c = half * 512 + lane * 8 + k;
      float f = 0.f;
#pragma unroll
      for (int e2 = 0; e2 < E_EXP; ++e2) f += te[e2] * v[e2][half * 8 + k];
      f = tanhf(f);
      const float* hwc = hw + (size_t)c * H_OUT;
#pragma unroll
      for (int h = 0; h < H_OUT; ++h) ph[h] += f * hwc[h];
    }
  }

#pragma unroll
  for (int h = 0; h < H_OUT; ++h) ph[h] = wred(ph[h]);
  if (lane == 0) {
#pragma unroll
    for (int h = 0; h < H_OUT; ++h)
      out[(size_t)b * H_OUT + h] = ph[h] + head_b[idx * H_OUT + h];
  }
}

// ---------------- launch ----------------

extern "C" void kernel_launch(void* const* d_in, const int* in_sizes, int n_in,
                              void* d_out, int out_size, void* d_ws, size_t ws_size,
                              hipStream_t stream) {
  const float* x     = (const float*)d_in[0];
  const float* te_W  = (const float*)d_in[1];
  const float* W0    = (const float*)d_in[2];
  const float* b0    = (const float*)d_in[3];
  const float* W1    = (const float*)d_in[4];
  const float* b1    = (const float*)d_in[5];
  const float* W2    = (const float*)d_in[6];
  const float* b2    = (const float*)d_in[7];
  const float* headW = (const float*)d_in[8];
  const float* headb = (const float*)d_in[9];
  float* out = (float*)d_out;

  char* ws = (char*)d_ws;
  size_t off = 0;
  auto alloc = [&](size_t bytes) {
    void* p = ws + off;
    off += (bytes + 255) & ~(size_t)255;
    return p;
  };
  unsigned short* obsB = (unsigned short*)alloc((size_t)B_SZ * OBS * 2);
  unsigned short* W0t  = (unsigned short*)alloc((size_t)8 * 1024 * 512 * 2);
  unsigned short* W1t  = (unsigned short*)alloc((size_t)8 * 1024 * 1024 * 2);
  unsigned short* W2t  = (unsigned short*)alloc((size_t)8 * 1024 * 1024 * 2);
  unsigned short* h0   = (unsigned short*)alloc((size_t)B_SZ * NTOT * 2);
  unsigned short* h1   = (unsigned short*)alloc((size_t)B_SZ * NTOT * 2);
  unsigned short* eo   = (unsigned short*)alloc((size_t)B_SZ * NTOT * 2);
  (void)ws_size; (void)in_sizes; (void)n_in; (void)out_size;

  k_obs_bf16<<<(B_SZ * OBS) / 256, 256, 0, stream>>>(x, obsB);
  k_wt<<<dim3(32, 16, 8), 256, 0, stream>>>(W0, W0t, 512);
  k_wt<<<dim3(32, 32, 8), 256, 0, stream>>>(W1, W1t, 1024);
  k_wt<<<dim3(32, 32, 8), 256, 0, stream>>>(W2, W2t, 1024);

  k_gemm256<true ><<<512, 512, 131072, stream>>>(obsB, 512,  0,    W0t, 512,  b0, h0);
  k_gemm256<true ><<<512, 512, 131072, stream>>>(h0,   NTOT, 1024, W1t, 1024, b1, h1);
  k_gemm256<false><<<512, 512, 131072, stream>>>(h1,   NTOT, 1024, W2t, 1024, b2, eo);

  k_gs_wave<<<B_SZ / 4, 256, 0, stream>>>(eo, x, te_W, headW, headb, out);
}

// Round 4
// 245.326 us; speedup vs baseline: 2.1327x; 1.0657x over previous
//
#include <hip/hip_runtime.h>
#include <stdint.h>

#define B_SZ   4096
#define OBS    512
#define T_TASKS 10
#define E_EXP  8
#define W_DIM  1024
#define H_OUT  12
#define XROW   522      // OBS + T
#define NTOT   8192     // E*W

using f32x4  = __attribute__((ext_vector_type(4))) float;
using bf16x8 = __attribute__((ext_vector_type(8))) short;

__device__ __forceinline__ unsigned short f2bf(float f) {
  union { float f; unsigned u; } x; x.f = f;
  unsigned r = x.u + 0x7FFF + ((x.u >> 16) & 1);   // RNE
  return (unsigned short)(r >> 16);
}
__device__ __forceinline__ float bf2f(unsigned short h) {
  union { unsigned u; float f; } x; x.u = ((unsigned)h) << 16;
  return x.f;
}

__device__ __forceinline__ void gload_lds16(const void* g, void* l) {
  __builtin_amdgcn_global_load_lds(
      (const __attribute__((address_space(1))) void*)g,
      (__attribute__((address_space(3))) void*)l,
      16, 0, 0);
}

#define VMCNT4  do { asm volatile("s_waitcnt vmcnt(4)" ::: "memory"); \
                     __builtin_amdgcn_sched_barrier(0); } while (0)
#define BARRIER do { asm volatile("s_barrier" ::: "memory"); \
                     __builtin_amdgcn_sched_barrier(0); } while (0)
#define SCHED0  __builtin_amdgcn_sched_barrier(0)

// ---------------- prep kernels ----------------

__global__ void k_obs_bf16(const float* __restrict__ x, unsigned short* __restrict__ obsB) {
  int i = blockIdx.x * 256 + threadIdx.x;          // over B*OBS, exact grid
  int b = i >> 9, c = i & 511;
  obsB[i] = f2bf(x[(size_t)b * XROW + c]);
}

// W [e][K][1024] f32  ->  Wt [e][1024][K] bf16
__global__ void k_wt(const float* __restrict__ Wsrc, unsigned short* __restrict__ Wt, int K) {
  __shared__ float tile[32][33];
  int e  = blockIdx.z;
  int n0 = blockIdx.x * 32, k0 = blockIdx.y * 32;
  const float* Ws = Wsrc + (size_t)e * K * W_DIM;
  unsigned short* Wd = Wt + (size_t)e * W_DIM * K;
  int tx = threadIdx.x & 31, ty = threadIdx.x >> 5;   // ty 0..7
#pragma unroll
  for (int r = 0; r < 4; ++r)
    tile[ty + r * 8][tx] = Ws[(size_t)(k0 + ty + r * 8) * W_DIM + n0 + tx];
  __syncthreads();
#pragma unroll
  for (int r = 0; r < 4; ++r)
    Wd[(size_t)(n0 + ty + r * 8) * K + k0 + tx] = f2bf(tile[tx][ty + r * 8]);
}

// ---------------- 256x256 GEMM, 4-phase/K-tile with 1-phase register lookahead ----------------
// C[b][e*1024+n] = act( A[b][:]_e @ Bt[e][n][:] + bias[e][n] ), C bf16.
// 512 thr = 8 waves (2M x 4N). BK=64, dbuf LDS 128 KB.
// Quadrants per K-tile: Q0(mh0,nh0) Q1(mh0,nh1) Q2(mh1,nh1) Q3(mh1,nh0).
// Every half-tile staged exactly 3 phases before its ds_read -> uniform vmcnt(4),
// ONE barrier per phase, ds_reads overlap MFMA via pre/post placement:
//   Q0: pre-read bf1(t)          stage B0(t+1)
//   Q1: post-read af<-A-h1(t)    stage B1(t+1)
//   Q2: (no reads)               stage A1(t+1)
//   Q3: post-read af<-A0(t+1), bf0<-B0(t+1) [from nbuf]   stage A0(t+2) [into buf]

template <bool RELU>
__global__ __launch_bounds__(512, 2) void k_gemm256(
    const unsigned short* __restrict__ A, int lda, int aExpStride,
    const unsigned short* __restrict__ Bt, int K,
    const float* __restrict__ bias,
    unsigned short* __restrict__ C)
{
  extern __shared__ char lds[];
  const int tid  = threadIdx.x;
  const int lane = tid & 63, wid = tid >> 6;
  const int wm = wid >> 2, wn = wid & 3;
  const int rlo = lane & 15, kg = lane >> 4;

  // bijective XCD swizzle: 512 blocks -> 8 XCDs x (8 mblk x 8 nblk)
  int bid = blockIdx.x;
  int xcd = bid & 7, loc = bid >> 3;
  int mblk = ((xcd & 1) << 3) | (loc & 7);
  int nblk = ((xcd >> 1) << 3) | (loc >> 3);
  int m0 = mblk * 256, n0g = nblk * 256;
  int e = n0g >> 10, n0e = n0g & 1023;

  const unsigned short* Ab = A + (size_t)e * aExpStride;
  const unsigned short* Bb = Bt + ((size_t)e * 1024 + n0e) * (size_t)K;

  // staging coords: half-tile = 128 rows x 8 chunks(16B) = 1024 chunks; 2/thread
  const int idx0 = tid, idx1 = 512 + tid;
  const int r0 = idx0 >> 3, p0 = idx0 & 7, c0 = p0 ^ (r0 & 7);  // inverse-swz source
  const int r1 = idx1 >> 3, p1 = idx1 & 7, c1 = p1 ^ (r1 & 7);

  const int NT = K >> 6;
  const size_t ldaz = (size_t)lda, ldkz = (size_t)K;

  auto stageA = [&](int buf, int h, int kt) {
    const unsigned short* g0 = Ab + (size_t)(m0 + h * 128 + r0) * ldaz + kt * 64 + c0 * 8;
    const unsigned short* g1 = Ab + (size_t)(m0 + h * 128 + r1) * ldaz + kt * 64 + c1 * 8;
    char* l = lds + buf * 65536 + h * 16384;
    gload_lds16(g0, l + idx0 * 16);
    gload_lds16(g1, l + idx1 * 16);
  };
  auto stageB = [&](int buf, int h, int kt) {
    const unsigned short* g0 = Bb + (size_t)(h * 128 + r0) * ldkz + kt * 64 + c0 * 8;
    const unsigned short* g1 = Bb + (size_t)(h * 128 + r1) * ldkz + kt * 64 + c1 * 8;
    char* l = lds + buf * 65536 + 32768 + h * 16384;
    gload_lds16(g0, l + idx0 * 16);
    gload_lds16(g1, l + idx1 * 16);
  };
  auto rdA = [&](int buf, int mh, int mi, int ks) -> bf16x8 {
    int r = mi * 32 + wm * 16 + rlo;
    int p = (ks * 4 + kg) ^ (r & 7);               // swizzled read
    return *(const bf16x8*)(lds + buf * 65536 + mh * 16384 + r * 128 + p * 16);
  };
  auto rdB = [&](int buf, int nh, int ni, int ks) -> bf16x8 {
    int r = ni * 64 + wn * 16 + rlo;
    int p = (ks * 4 + kg) ^ (r & 7);
    return *(const bf16x8*)(lds + buf * 65536 + 32768 + nh * 16384 + r * 128 + p * 16);
  };

  f32x4 acc[8][4];
#pragma unroll
  for (int i = 0; i < 8; ++i)
#pragma unroll
    for (int j = 0; j < 4; ++j) acc[i][j] = f32x4{0.f, 0.f, 0.f, 0.f};

  bf16x8 af[8], bf0[4], bf1[4];

  // prologue: stage A0(0),B0(0),B1(0),A1(0),A0(1); drain first 4 loads; read frags for Q0(0)
  stageA(0, 0, 0); stageB(0, 0, 0); stageB(0, 1, 0); stageA(0, 1, 0);
  stageA(1, 0, (1 < NT - 1) ? 1 : NT - 1);
  asm volatile("s_waitcnt vmcnt(6)" ::: "memory");
  SCHED0;
  BARRIER;
#pragma unroll
  for (int mi = 0; mi < 4; ++mi)
#pragma unroll
    for (int ks = 0; ks < 2; ++ks) af[mi * 2 + ks] = rdA(0, 0, mi, ks);
#pragma unroll
  for (int ni = 0; ni < 2; ++ni)
#pragma unroll
    for (int ks = 0; ks < 2; ++ks) bf0[ni * 2 + ks] = rdB(0, 0, ni, ks);

  for (int t = 0; t < NT; ++t) {
    int buf = t & 1, nbuf = buf ^ 1;
    int tn  = (t + 1 < NT) ? t + 1 : NT - 1;       // clamped: keeps vmcnt counts exact
    int tn2 = (t + 2 < NT) ? t + 2 : NT - 1;

    // ---- Q0: MFMA(af:h0, bf0) ----
    VMCNT4;                                        // B1(t) landed (staged Q1(t-1))
    BARRIER;
#pragma unroll
    for (int ni = 0; ni < 2; ++ni)
#pragma unroll
      for (int ks = 0; ks < 2; ++ks) bf1[ni * 2 + ks] = rdB(buf, 1, ni, ks);
    stageB(nbuf, 0, tn);
    SCHED0;
    __builtin_amdgcn_s_setprio(1);
#pragma unroll
    for (int ks = 0; ks < 2; ++ks)
#pragma unroll
      for (int mi = 0; mi < 4; ++mi)
#pragma unroll
        for (int ni = 0; ni < 2; ++ni)
          acc[mi][ni] = __builtin_amdgcn_mfma_f32_16x16x32_bf16(af[mi * 2 + ks], bf0[ni * 2 + ks], acc[mi][ni], 0, 0, 0);
    __builtin_amdgcn_s_setprio(0);
    SCHED0;

    // ---- Q1: MFMA(af:h0, bf1); post-read af <- A-h1(t) ----
    VMCNT4;                                        // A1(t) landed (staged Q2(t-1))
    BARRIER;
    stageB(nbuf, 1, tn);
    SCHED0;
    __builtin_amdgcn_s_setprio(1);
#pragma unroll
    for (int ks = 0; ks < 2; ++ks)
#pragma unroll
      for (int mi = 0; mi < 4; ++mi)
#pragma unroll
        for (int ni = 0; ni < 2; ++ni)
          acc[mi][2 + ni] = __builtin_amdgcn_mfma_f32_16x16x32_bf16(af[mi * 2 + ks], bf1[ni * 2 + ks], acc[mi][2 + ni], 0, 0, 0);
    __builtin_amdgcn_s_setprio(0);
    SCHED0;
#pragma unroll
    for (int mi = 0; mi < 4; ++mi)
#pragma unroll
      for (int ks = 0; ks < 2; ++ks) af[mi * 2 + ks] = rdA(buf, 1, mi, ks);

    // ---- Q2: MFMA(af:h1, bf1) ----
    VMCNT4;                                        // (A0(t+1) certainly landed)
    BARRIER;
    stageA(nbuf, 1, tn);
    SCHED0;
    __builtin_amdgcn_s_setprio(1);
#pragma unroll
    for (int ks = 0; ks < 2; ++ks)
#pragma unroll
      for (int mi = 0; mi < 4; ++mi)
#pragma unroll
        for (int ni = 0; ni < 2; ++ni)
          acc[4 + mi][2 + ni] = __builtin_amdgcn_mfma_f32_16x16x32_bf16(af[mi * 2 + ks], bf1[ni * 2 + ks], acc[4 + mi][2 + ni], 0, 0, 0);
    __builtin_amdgcn_s_setprio(0);
    SCHED0;

    // ---- Q3: MFMA(af:h1, bf0); post-read af<-A0(t+1), bf0<-B0(t+1) from nbuf ----
    VMCNT4;                                        // A0(t+1),B0(t+1) landed
    BARRIER;
    stageA(buf, 0, tn2);                           // A0(t+2) -> buf(t+2)==buf
    SCHED0;
    __builtin_amdgcn_s_setprio(1);
#pragma unroll
    for (int ks = 0; ks < 2; ++ks)
#pragma unroll
      for (int mi = 0; mi < 4; ++mi)
#pragma unroll
        for (int ni = 0; ni < 2; ++ni)
          acc[4 + mi][ni] = __builtin_amdgcn_mfma_f32_16x16x32_bf16(af[mi * 2 + ks], bf0[ni * 2 + ks], acc[4 + mi][ni], 0, 0, 0);
    __builtin_amdgcn_s_setprio(0);
    SCHED0;
#pragma unroll
    for (int mi = 0; mi < 4; ++mi)
#pragma unroll
      for (int ks = 0; ks < 2; ++ks) af[mi * 2 + ks] = rdA(nbuf, 0, mi, ks);
#pragma unroll
    for (int ni = 0; ni < 2; ++ni)
#pragma unroll
      for (int ks = 0; ks < 2; ++ks) bf0[ni * 2 + ks] = rdB(nbuf, 0, ni, ks);
  }

  // epilogue: bias (+ReLU) + bf16 store
  int rbase = kg * 4;
#pragma unroll
  for (int fi = 0; fi < 8; ++fi) {
    int mh = fi >> 2, mi = fi & 3;
    int rowg = m0 + mh * 128 + mi * 32 + wm * 16 + rbase;
#pragma unroll
    for (int fj = 0; fj < 4; ++fj) {
      int nh = fj >> 1, ni = fj & 1;
      int colr = nh * 128 + ni * 64 + wn * 16 + rlo;
      int colg = n0g + colr;
      float bv = bias[e * W_DIM + n0e + colr];
#pragma unroll
      for (int j = 0; j < 4; ++j) {
        float v = acc[fi][fj][j] + bv;
        if (RELU) v = fmaxf(v, 0.0f);
        C[(size_t)(rowg + j) * NTOT + colg] = f2bf(v);
      }
    }
  }
}

// ---------------- Gram-Schmidt + feat + head: one WAVE per batch row ----------------

__device__ __forceinline__ float wred(float s) {
#pragma unroll
  for (int m = 32; m; m >>= 1) s += __shfl_xor(s, m, 64);
  return s;
}

__global__ __launch_bounds__(256, 1) void k_gs_wave(
    const unsigned short* __restrict__ eo,   // [B][8192] bf16
    const float* __restrict__ x,
    const float* __restrict__ te_W,          // [10][8]
    const float* __restrict__ head_W,        // [10][1024][12]
    const float* __restrict__ head_b,        // [10][12]
    float* __restrict__ out)                 // [B][12]
{
  int wid = threadIdx.x >> 6, lane = threadIdx.x & 63;
  int b = blockIdx.x * 4 + wid;

  float v[8][16];
  const unsigned short* row = eo + (size_t)b * NTOT;
#pragma unroll
  for (int i = 0; i < E_EXP; ++i) {
#pragma unroll
    for (int half = 0; half < 2; ++half) {
      bf16x8 t = *(const bf16x8*)&row[i * 1024 + half * 512 + lane * 8];
#pragma unroll
      for (int k = 0; k < 8; ++k) v[i][half * 8 + k] = bf2f((unsigned short)t[k]);
    }
  }

  int idx = 0; float mv = x[(size_t)b * XROW + OBS];
#pragma unroll
  for (int t = 1; t < T_TASKS; ++t) {
    float val = x[(size_t)b * XROW + OBS + t];
    if (val > mv) { mv = val; idx = t; }
  }

  float cf[7];
#pragma unroll
  for (int i = 0; i < E_EXP; ++i) {
#pragma unroll
    for (int j = 0; j < 7; ++j) {
      if (j < i) {
        float p = 0.f;
#pragma unroll
        for (int c = 0; c < 16; ++c) p += v[i][c] * v[j][c];
        cf[j] = wred(p);
      }
    }
#pragma unroll
    for (int c = 0; c < 16; ++c) {
      float w = v[i][c];
#pragma unroll
      for (int j = 0; j < 7; ++j)
        if (j < i) w -= cf[j] * v[j][c];
      v[i][c] = w;
    }
    float p = 0.f;
#pragma unroll
    for (int c = 0; c < 16; ++c) p += v[i][c] * v[i][c];
    float nrm = sqrtf(wred(p));
    float s = 1.0f / (nrm + 1e-8f);
#pragma unroll
    for (int c = 0; c < 16; ++c) v[i][c] *= s;
  }

  float te[E_EXP];
#pragma unroll
  for (int e2 = 0; e2 < E_EXP; ++e2) te[e2] = te_W[idx * E_EXP + e2];

  float ph[H_OUT];
#pragma unroll
  for (int h = 0; h < H_OUT; ++h) ph[h] = 0.f;
  const float* hw = head_W + (size_t)idx * W_DIM * H_OUT;

#pragma unroll
  for (int half = 0; half < 2; ++half) {
#pragma unroll
    for (int k = 0; k < 8; ++k) {
      int c = half * 512 + lane * 8 + k;
      float f = 0.f;
#pragma unroll
      for (int e2 = 0; e2 < E_EXP; ++e2) f += te[e2] * v[e2][half * 8 + k];
      f = tanhf(f);
      const float* hwc = hw + (size_t)c * H_OUT;
#pragma unroll
      for (int h = 0; h < H_OUT; ++h) ph[h] += f * hwc[h];
    }
  }

#pragma unroll
  for (int h = 0; h < H_OUT; ++h) ph[h] = wred(ph[h]);
  if (lane == 0) {
#pragma unroll
    for (int h = 0; h < H_OUT; ++h)
      out[(size_t)b * H_OUT + h] = ph[h] + head_b[idx * H_OUT + h];
  }
}

// ---------------- launch ----------------

extern "C" void kernel_launch(void* const* d_in, const int* in_sizes, int n_in,
                              void* d_out, int out_size, void* d_ws, size_t ws_size,
                              hipStream_t stream) {
  const float* x     = (const float*)d_in[0];
  const float* te_W  = (const float*)d_in[1];
  const float* W0    = (const float*)d_in[2];
  const float* b0    = (const float*)d_in[3];
  const float* W1    = (const float*)d_in[4];
  const float* b1    = (const float*)d_in[5];
  const float* W2    = (const float*)d_in[6];
  const float* b2    = (const float*)d_in[7];
  const float* headW = (const float*)d_in[8];
  const float* headb = (const float*)d_in[9];
  float* out = (float*)d_out;

  char* ws = (char*)d_ws;
  size_t off = 0;
  auto alloc = [&](size_t bytes) {
    void* p = ws + off;
    off += (bytes + 255) & ~(size_t)255;
    return p;
  };
  unsigned short* obsB = (unsigned short*)alloc((size_t)B_SZ * OBS * 2);
  unsigned short* W0t  = (unsigned short*)alloc((size_t)8 * 1024 * 512 * 2);
  unsigned short* W1t  = (unsigned short*)alloc((size_t)8 * 1024 * 1024 * 2);
  unsigned short* W2t  = (unsigned short*)alloc((size_t)8 * 1024 * 1024 * 2);
  unsigned short* h0   = (unsigned short*)alloc((size_t)B_SZ * NTOT * 2);
  unsigned short* h1   = (unsigned short*)alloc((size_t)B_SZ * NTOT * 2);
  unsigned short* eo   = (unsigned short*)alloc((size_t)B_SZ * NTOT * 2);
  (void)ws_size; (void)in_sizes; (void)n_in; (void)out_size;

  k_obs_bf16<<<(B_SZ * OBS) / 256, 256, 0, stream>>>(x, obsB);
  k_wt<<<dim3(32, 16, 8), 256, 0, stream>>>(W0, W0t, 512);
  k_wt<<<dim3(32, 32, 8), 256, 0, stream>>>(W1, W1t, 1024);
  k_wt<<<dim3(32, 32, 8), 256, 0, stream>>>(W2, W2t, 1024);

  k_gemm256<true ><<<512, 512, 131072, stream>>>(obsB, 512,  0,    W0t, 512,  b0, h0);
  k_gemm256<true ><<<512, 512, 131072, stream>>>(h0,   NTOT, 1024, W1t, 1024, b1, h1);
  k_gemm256<false><<<512, 512, 131072, stream>>>(h1,   NTOT, 1024, W2t, 1024, b2, eo);

  k_gs_wave<<<B_SZ / 4, 256, 0, stream>>>(eo, x, te_W, headW, headb, out);
}